// Round 1
// baseline (795.433 us; speedup 1.0000x reference)
//
#include <hip/hip_runtime.h>
#include <hip/hip_bf16.h>
#include <cstdint>
#include <cstddef>

typedef __hip_bfloat16 BF;
typedef __attribute__((ext_vector_type(8))) short bhalf8;   // 8 bf16 (MFMA A/B frag)
typedef __attribute__((ext_vector_type(4))) float floatx4;  // MFMA C/D frag

#define NB 8
#define NC 512
#define NHW 4096
#define NG 32

__device__ __forceinline__ float b2f(short h) {
    union { unsigned u; float f; } c;
    c.u = ((unsigned)(unsigned short)h) << 16;
    return c.f;
}
__device__ __forceinline__ short f2b(float f) {
    __hip_bfloat16 h = __float2bfloat16(f);
    short s;
    __builtin_memcpy(&s, &h, 2);
    return s;
}

// 16B global -> LDS direct (wave-uniform LDS base + lane*16)
__device__ __forceinline__ void gload16(const BF* g, BF* l) {
    __builtin_amdgcn_global_load_lds(
        (const __attribute__((address_space(1))) void*)g,
        (__attribute__((address_space(3))) void*)l, 16, 0, 0);
}

// T1: bijective XCD-aware tile swizzle (m204). Valid (bijective) because every
// per-z-slice grid we launch has nwg % 8 == 0; guarded anyway.
__device__ __forceinline__ void xcd_swizzle(int& bx, int& by) {
    const int gx = gridDim.x;
    const int nwg = gx * gridDim.y;
    if ((nwg & 7) == 0) {
        const int lin = by * gx + bx;
        const int cpx = nwg >> 3;
        const int s = (lin & 7) * cpx + (lin >> 3);
        bx = s % gx;
        by = s / gx;
    }
}

// ---------------------------------------------------------------------------
// one launch converts all four 512x512 weight matrices to bf16
__global__ __launch_bounds__(256) void f2b_convert4(const float* __restrict__ s0,
                                                    const float* __restrict__ s1,
                                                    const float* __restrict__ s2,
                                                    const float* __restrict__ s3,
                                                    BF* __restrict__ dst) {
    const int which = blockIdx.x >> 8;            // 256 blocks per matrix
    const float* src = (which == 0) ? s0 : (which == 1) ? s1 : (which == 2) ? s2 : s3;
    BF* d = dst + (long)which * (NC * NC);
    const int i = ((blockIdx.x & 255) * 256 + threadIdx.x) * 4;
    float4 v = *(const float4*)&src[i];
    d[i]     = __float2bfloat16(v.x);
    d[i + 1] = __float2bfloat16(v.y);
    d[i + 2] = __float2bfloat16(v.z);
    d[i + 3] = __float2bfloat16(v.w);
}

// ---------------------------------------------------------------------------
__global__ __launch_bounds__(256) void gn_stats(const float* __restrict__ x,
                                                float* __restrict__ stats) {
    const int bg = blockIdx.x;
    const long base = (long)bg * 65536;
    float s = 0.f, q = 0.f;
    for (int i = threadIdx.x * 4; i < 65536; i += 256 * 4) {
        float4 v4 = *(const float4*)&x[base + i];
        s += v4.x + v4.y + v4.z + v4.w;
        q += v4.x * v4.x + v4.y * v4.y + v4.z * v4.z + v4.w * v4.w;
    }
#pragma unroll
    for (int o = 32; o; o >>= 1) { s += __shfl_down(s, o); q += __shfl_down(q, o); }
    __shared__ float rs[4], rq[4];
    const int w = threadIdx.x >> 6;
    if ((threadIdx.x & 63) == 0) { rs[w] = s; rq[w] = q; }
    __syncthreads();
    if (threadIdx.x == 0) {
        s = rs[0] + rs[1] + rs[2] + rs[3];
        q = rq[0] + rq[1] + rq[2] + rq[3];
        float mean = s * (1.f / 65536.f);
        float var = q * (1.f / 65536.f) - mean * mean;
        stats[2 * bg]     = mean;
        stats[2 * bg + 1] = rsqrtf(fmaxf(var, 0.f) + 1e-6f);
    }
}

// ---------------------------------------------------------------------------
__global__ __launch_bounds__(256) void gn_apply(const float* __restrict__ x,
                                                const float* __restrict__ gamma,
                                                const float* __restrict__ beta,
                                                const float* __restrict__ stats,
                                                BF* __restrict__ n) {
    __shared__ float tile[64][65];
    const int b = blockIdx.z, c0 = blockIdx.y * 64, s0 = blockIdx.x * 64;
    const long xbase = ((long)b * NC + c0) * NHW + s0;
#pragma unroll
    for (int i = 0; i < 16; i++) {
        int lin = i * 256 + threadIdx.x;
        int cl = lin >> 6, sl = lin & 63;
        int c = c0 + cl;
        float2 mr = ((const float2*)stats)[b * NG + (c >> 4)];
        float v = x[xbase + (long)cl * NHW + sl];
        v = (v - mr.x) * mr.y * gamma[c] + beta[c];
        tile[cl][sl] = v;
    }
    __syncthreads();
    const long nbase = ((long)b * NHW + s0) * NC + c0;
#pragma unroll
    for (int i = 0; i < 16; i++) {
        int lin = i * 256 + threadIdx.x;
        int sl = lin >> 6, cl = lin & 63;
        n[nbase + (long)sl * NC + cl] = __float2bfloat16(tile[cl][sl]);
    }
}

// ---------------------------------------------------------------------------
// GEMM 128x128 tile, BK=32: C[m][n] = scale*sum_k A[m][k]*B[n][k] (+bias[n])
// A [M,K], B [N,K] both K-contig bf16. m97-style global_load_lds staging.
// 4 waves, each 64x64 (4x4 MFMA 16x16x32).
// RESID variant: writes f32 out[col*M+row] = acc*scale + resid[...] (fused
// transpose + residual add for the final Wo projection).
// ---------------------------------------------------------------------------
template <bool BIAS, bool TRANS, bool RESID>
__global__ __launch_bounds__(256, 2) void gemm128(
    const BF* __restrict__ A, long aStride,
    const BF* __restrict__ Bm, long bStride,
    BF* __restrict__ C, long cStride,
    const float* __restrict__ bias,
    const float* __restrict__ resid, float* __restrict__ outF,
    int M, int N, int K, float scale)
{
    __shared__ __align__(16) BF sA[128 * 32];
    __shared__ __align__(16) BF sB[128 * 32];
    const int tid = threadIdx.x;
    const int wave = tid >> 6, lane = tid & 63;
    int bxi = blockIdx.x, byi = blockIdx.y;
    xcd_swizzle(bxi, byi);
    const int bm = byi * 128, bn = bxi * 128;
    const BF* Ab = A + (long)blockIdx.z * aStride + (long)bm * K;
    const BF* Bb = Bm + (long)blockIdx.z * bStride + (long)bn * K;

    // staging: wave w covers rows [w*32, w*32+32), 2 instrs of 16 rows each.
    const int srow = wave * 32 + (lane >> 2);
    const int sk = (lane & 3) * 8;
    const BF* gA0 = Ab + (long)srow * K + sk;
    const BF* gA1 = gA0 + (long)16 * K;
    const BF* gB0 = Bb + (long)srow * K + sk;
    const BF* gB1 = gB0 + (long)16 * K;
    BF* lA0 = &sA[(wave * 32) * 32];
    BF* lA1 = &sA[(wave * 32 + 16) * 32];
    BF* lB0 = &sB[(wave * 32) * 32];
    BF* lB1 = &sB[(wave * 32 + 16) * 32];

    floatx4 acc[4][4];
#pragma unroll
    for (int i = 0; i < 4; i++)
#pragma unroll
        for (int j = 0; j < 4; j++) acc[i][j] = (floatx4){0.f, 0.f, 0.f, 0.f};

    const int wm = (wave >> 1) * 64, wn = (wave & 1) * 64;
    const int lr = lane & 15, lk = (lane >> 4) * 8;

    for (int k0 = 0; k0 < K; k0 += 32) {
        __syncthreads();               // prev tile consumed
        gload16(gA0 + k0, lA0);
        gload16(gA1 + k0, lA1);
        gload16(gB0 + k0, lB0);
        gload16(gB1 + k0, lB1);
        __syncthreads();               // drains vmcnt -> tile visible
        bhalf8 af[4], bfr[4];
#pragma unroll
        for (int i = 0; i < 4; i++)
            af[i] = *(const bhalf8*)&sA[(wm + i * 16 + lr) * 32 + lk];
#pragma unroll
        for (int i = 0; i < 4; i++)
            bfr[i] = *(const bhalf8*)&sB[(wn + i * 16 + lr) * 32 + lk];
#pragma unroll
        for (int mi = 0; mi < 4; mi++)
#pragma unroll
            for (int ni = 0; ni < 4; ni++)
                acc[mi][ni] = __builtin_amdgcn_mfma_f32_16x16x32_bf16(
                    af[mi], bfr[ni], acc[mi][ni], 0, 0, 0);
    }

    if (RESID) {
        float* Ob = outF + (long)blockIdx.z * cStride;
        const float* Xb = resid + (long)blockIdx.z * cStride;
#pragma unroll
        for (int ni = 0; ni < 4; ni++) {
            const int col = bn + wn + ni * 16 + lr;
#pragma unroll
            for (int mi = 0; mi < 4; mi++) {
                const int row0 = bm + wm + mi * 16 + (lane >> 4) * 4;
                const long a = (long)col * M + row0;   // [C][HW] == output layout
                float4 xv = *(const float4*)&Xb[a];
                float4 ov;
                ov.x = acc[mi][ni][0] * scale + xv.x;
                ov.y = acc[mi][ni][1] * scale + xv.y;
                ov.z = acc[mi][ni][2] * scale + xv.z;
                ov.w = acc[mi][ni][3] * scale + xv.w;
                *(float4*)&Ob[a] = ov;
            }
        }
        return;
    }

    BF* Cb = C + (long)blockIdx.z * cStride;
#pragma unroll
    for (int ni = 0; ni < 4; ni++) {
        const int col = bn + wn + ni * 16 + lr;
        const float bv = BIAS ? bias[col] : 0.0f;
#pragma unroll
        for (int mi = 0; mi < 4; mi++) {
            const int row0 = bm + wm + mi * 16 + (lane >> 4) * 4;
#pragma unroll
            for (int r = 0; r < 4; r++) {
                float v = acc[mi][ni][r] * scale + bv;
                if (TRANS) Cb[(long)col * M + row0 + r] = __float2bfloat16(v);
                else       Cb[(long)(row0 + r) * N + col] = __float2bfloat16(v);
            }
        }
    }
}

// ---------------------------------------------------------------------------
// GEMM 64(M)x128(N) tile, BK=32 — for grid-starved shapes (PV at small chunk).
// 4 waves in 2x2, each 32x64 (2x4 MFMA).
// ---------------------------------------------------------------------------
__global__ __launch_bounds__(256, 2) void gemm64(
    const BF* __restrict__ A, long aStride,
    const BF* __restrict__ Bm, long bStride,
    BF* __restrict__ C, long cStride,
    int N, int K, float scale)
{
    __shared__ __align__(16) BF sA[64 * 32];
    __shared__ __align__(16) BF sB[128 * 32];
    const int tid = threadIdx.x;
    const int wave = tid >> 6, lane = tid & 63;
    int bxi = blockIdx.x, byi = blockIdx.y;
    xcd_swizzle(bxi, byi);
    const int bm = byi * 64, bn = bxi * 128;
    const BF* Ab = A + (long)blockIdx.z * aStride + (long)bm * K;
    const BF* Bb = Bm + (long)blockIdx.z * bStride + (long)bn * K;

    const int rowoff = lane >> 2, sk = (lane & 3) * 8;
    const BF* gA0 = Ab + (long)(wave * 16 + rowoff) * K + sk;      // 1 instr: 16 rows
    const BF* gB0 = Bb + (long)(wave * 32 + rowoff) * K + sk;      // 2 instrs
    const BF* gB1 = gB0 + (long)16 * K;
    BF* lA0 = &sA[(wave * 16) * 32];
    BF* lB0 = &sB[(wave * 32) * 32];
    BF* lB1 = &sB[(wave * 32 + 16) * 32];

    floatx4 acc[2][4];
#pragma unroll
    for (int i = 0; i < 2; i++)
#pragma unroll
        for (int j = 0; j < 4; j++) acc[i][j] = (floatx4){0.f, 0.f, 0.f, 0.f};

    const int wm = (wave >> 1) * 32, wn = (wave & 1) * 64;
    const int lr = lane & 15, lk = (lane >> 4) * 8;

    for (int k0 = 0; k0 < K; k0 += 32) {
        __syncthreads();
        gload16(gA0 + k0, lA0);
        gload16(gB0 + k0, lB0);
        gload16(gB1 + k0, lB1);
        __syncthreads();
        bhalf8 af[2], bfr[4];
#pragma unroll
        for (int i = 0; i < 2; i++)
            af[i] = *(const bhalf8*)&sA[(wm + i * 16 + lr) * 32 + lk];
#pragma unroll
        for (int i = 0; i < 4; i++)
            bfr[i] = *(const bhalf8*)&sB[(wn + i * 16 + lr) * 32 + lk];
#pragma unroll
        for (int mi = 0; mi < 2; mi++)
#pragma unroll
            for (int ni = 0; ni < 4; ni++)
                acc[mi][ni] = __builtin_amdgcn_mfma_f32_16x16x32_bf16(
                    af[mi], bfr[ni], acc[mi][ni], 0, 0, 0);
    }

    BF* Cb = C + (long)blockIdx.z * cStride;
#pragma unroll
    for (int ni = 0; ni < 4; ni++) {
        const int col = bn + wn + ni * 16 + lr;
#pragma unroll
        for (int mi = 0; mi < 2; mi++) {
            const int row0 = bm + wm + mi * 16 + (lane >> 4) * 4;
#pragma unroll
            for (int r = 0; r < 4; r++)
                Cb[(long)(row0 + r) * N + col] = __float2bfloat16(acc[mi][ni][r] * scale);
        }
    }
}

// ---------------------------------------------------------------------------
__global__ __launch_bounds__(256) void softmax4096(BF* __restrict__ S) {
    const long base = (long)blockIdx.x * 4096 + threadIdx.x * 16;
    const int tid = threadIdx.x, w = tid >> 6;
    bhalf8 u = *(bhalf8*)&S[base];
    bhalf8 u2 = *(bhalf8*)&S[base + 8];
    float v[16];
    float m = -1e30f;
#pragma unroll
    for (int j = 0; j < 8; j++) { v[j] = b2f(u[j]); v[8 + j] = b2f(u2[j]); }
#pragma unroll
    for (int j = 0; j < 16; j++) m = fmaxf(m, v[j]);
#pragma unroll
    for (int o = 32; o; o >>= 1) m = fmaxf(m, __shfl_xor(m, o));
    __shared__ float rm[4], rs[4];
    if ((tid & 63) == 0) rm[w] = m;
    __syncthreads();
    m = fmaxf(fmaxf(rm[0], rm[1]), fmaxf(rm[2], rm[3]));
    float s = 0.f;
#pragma unroll
    for (int j = 0; j < 16; j++) { v[j] = __expf(v[j] - m); s += v[j]; }
#pragma unroll
    for (int o = 32; o; o >>= 1) s += __shfl_xor(s, o);
    if ((tid & 63) == 0) rs[w] = s;
    __syncthreads();
    s = rs[0] + rs[1] + rs[2] + rs[3];
    const float inv = 1.0f / s;
#pragma unroll
    for (int j = 0; j < 8; j++) { u[j] = f2b(v[j] * inv); u2[j] = f2b(v[8 + j] * inv); }
    *(bhalf8*)&S[base] = u;
    *(bhalf8*)&S[base + 8] = u2;
}

// ---------------------------------------------------------------------------
extern "C" void kernel_launch(void* const* d_in, const int* in_sizes, int n_in,
                              void* d_out, int out_size, void* d_ws, size_t ws_size,
                              hipStream_t stream) {
    const float* x     = (const float*)d_in[0];
    const float* gamma = (const float*)d_in[1];
    const float* beta  = (const float*)d_in[2];
    const float* Wq    = (const float*)d_in[3];
    const float* bq    = (const float*)d_in[4];
    const float* Wk    = (const float*)d_in[5];
    const float* bk    = (const float*)d_in[6];
    const float* Wv    = (const float*)d_in[7];
    const float* bv    = (const float*)d_in[8];
    const float* Wo    = (const float*)d_in[9];
    float* out = (float*)d_out;

    const long ACTB = (long)NHW * NC;        // 2M elems / batch
    const long SB   = (long)NHW * NHW;       // 16.7M elems / batch
    const long WSZ  = (long)NC * NC;

    // layout: stats | wb | q | kk | vT | R (n, then S — disjoint lifetimes)
    char* ws = (char*)d_ws;
    float* stats = (float*)ws;
    BF* wb = (BF*)(ws + 4096);
    BF* q  = wb + 4 * WSZ;
    BF* kk = q + NB * ACTB;
    BF* vT = kk + NB * ACTB;
    BF* R  = vT + NB * ACTB;
    BF* n = R;   // live: GN -> QKV GEMMs
    BF* S = R;   // live: attention chunks

    const size_t base_need = 4096ull + (size_t)4 * WSZ * 2 + (size_t)3 * NB * ACTB * 2;
    long sroom = (ws_size > base_need) ? (long)((ws_size - base_need) / (SB * 2)) : 1;
    int chunk = (int)(sroom < 1 ? 1 : (sroom > NB ? NB : sroom));
    while (NB % chunk) chunk--;              // 8,4,2,1

    f2b_convert4<<<1024, 256, 0, stream>>>(Wq, Wk, Wv, Wo, wb);

    gn_stats<<<NB * NG, 256, 0, stream>>>(x, stats);
    gn_apply<<<dim3(NHW / 64, NC / 64, NB), 256, 0, stream>>>(x, gamma, beta, stats, n);

    gemm128<true, false, false><<<dim3(NC / 128, NHW / 128, NB), 256, 0, stream>>>(
        n, ACTB, wb + 0 * WSZ, 0, q, ACTB, bq, nullptr, nullptr, NHW, NC, NC, 1.0f);
    gemm128<true, false, false><<<dim3(NC / 128, NHW / 128, NB), 256, 0, stream>>>(
        n, ACTB, wb + 1 * WSZ, 0, kk, ACTB, bk, nullptr, nullptr, NHW, NC, NC, 1.0f);
    gemm128<true, true, false><<<dim3(NC / 128, NHW / 128, NB), 256, 0, stream>>>(
        n, ACTB, wb + 2 * WSZ, 0, vT, ACTB, bv, nullptr, nullptr, NHW, NC, NC, 1.0f);

    const float iscl = 0.044194173824159216f;  // 1/sqrt(512)
    for (int b0 = 0; b0 < NB; b0 += chunk) {
        gemm128<false, false, false><<<dim3(NHW / 128, NHW / 128, chunk), 256, 0, stream>>>(
            q + b0 * ACTB, ACTB, kk + b0 * ACTB, ACTB, S, SB, nullptr, nullptr, nullptr,
            NHW, NHW, NC, iscl);
        softmax4096<<<NHW * chunk, 256, 0, stream>>>(S);
        if (chunk >= 4)
            gemm128<false, false, false><<<dim3(NC / 128, NHW / 128, chunk), 256, 0, stream>>>(
                S, SB, vT + b0 * ACTB, ACTB, q + b0 * ACTB, ACTB, nullptr, nullptr, nullptr,
                NHW, NC, NHW, 1.0f);
        else
            gemm64<<<dim3(NC / 128, NHW / 64, chunk), 256, 0, stream>>>(
                S, SB, vT + b0 * ACTB, ACTB, q + b0 * ACTB, ACTB, NC, NHW, 1.0f);
    }

    // final projection fused with transpose + residual add (writes f32 output)
    gemm128<false, true, true><<<dim3(NC / 128, NHW / 128, NB), 256, 0, stream>>>(
        q, ACTB, wb + 3 * WSZ, 0, nullptr, ACTB, nullptr, x, out, NHW, NC, NC, 1.0f);
}